// Round 1
// 78.713 us; speedup vs baseline: 1.1842x; 1.1842x over previous
//
#include <hip/hip_runtime.h>

// Instance fixed by setup_inputs(): N=1024 gaussians, H=W=256.
// SINGLE fused kernel: one block per image row.
//   Phase A: each thread preprocesses 4 gaussians directly from raw inputs
//            (redundant per block, ~1600 cy — cheaper than a launch),
//            culls vs this row (row-max exponent < log2(1e-8) => drop),
//            ballot-compacts survivors + z-keys into LDS in original order.
//   Phase B: stable in-block rank sort of the M survivors by (zbits, idx)
//            — identical order to "global argsort by z, then cull".
//   Phase C: front-to-back composite over the sorted survivors.
#define IMG_H 256
#define IMG_W 256
#define NG 1024
#define SH_BASE_F 0.28209479177387814f
#define L2E 1.4426950408889634f
#define LOG2EPS -26.575424759098898f   // log2(1e-8) cull threshold

__global__ __launch_bounds__(256) void fused_render_kernel(
    const float* __restrict__ mean,
    const float* __restrict__ qvec,
    const float* __restrict__ svecb,
    const float* __restrict__ shc,
    const float* __restrict__ alphab,
    const float* __restrict__ c2w,
    float* __restrict__ out,
    int N)
{
    __shared__ float4 comp[NG][2];        // 32 KB: [mx,qa,B,Cc][r,g,b,-]
    __shared__ ulonglong2 skey2[NG / 2];  // 8 KB, 16B-aligned for b128 reads
    __shared__ int wcnt[4];
    unsigned long long* skey = (unsigned long long*)skey2;

    const int tid = threadIdx.x;
    const int row = blockIdx.x;
    const float py = ((float)row + 0.5f - (float)IMG_H * 0.5f) / (float)IMG_W;
    const int wlane = tid & 63;
    const int wid = tid >> 6;
    const unsigned long long lanemask = (1ull << wlane) - 1ull;

    // Uniform camera matrix (scalar loads, L2-resident).
    float C[16];
#pragma unroll
    for (int k = 0; k < 16; ++k) C[k] = c2w[k];
    const float t0 = C[3], t1 = C[7], t2 = C[11];
    const float Rw00 = C[0], Rw01 = C[4], Rw02 = C[8];
    const float Rw10 = C[1], Rw11 = C[5], Rw12 = C[9];
    const float Rw20 = C[2], Rw21 = C[6], Rw22 = C[10];

    // ---------------- Phase A: preprocess + cull + compact ----------------
    int cnt = 0;   // running compacted count (uniform across block)
    for (int r = 0; r < 4; ++r) {
        const int n = r * 256 + tid;
        bool keep = false;
        float mx = 0.f, qa = 0.f, B = 0.f, Cc = 0.f, cr = 0.f, cg = 0.f, cb = 0.f;
        unsigned long long zk = 0;
        if (n < N) {
            const float d0 = mean[3 * n + 0] - t0;
            const float d1 = mean[3 * n + 1] - t1;
            const float d2 = mean[3 * n + 2] - t2;
            const float p0 = Rw00 * d0 + Rw01 * d1 + Rw02 * d2;
            const float p1 = Rw10 * d0 + Rw11 * d1 + Rw12 * d2;
            const float p2 = Rw20 * d0 + Rw21 * d1 + Rw22 * d2;

            const float z  = fmaxf(p2, 0.001f);
            const float iz = 1.0f / z;
            mx = p0 * iz;
            const float my = p1 * iz;

            float qw = qvec[4 * n + 0];
            float qx = qvec[4 * n + 1];
            float qy = qvec[4 * n + 2];
            float qz = qvec[4 * n + 3];
            const float qinv = 1.0f / sqrtf(qw * qw + qx * qx + qy * qy + qz * qz);
            qw *= qinv; qx *= qinv; qy *= qinv; qz *= qinv;
            const float R00 = 1.f - 2.f * (qy * qy + qz * qz);
            const float R01 = 2.f * (qx * qy - qw * qz);
            const float R02 = 2.f * (qx * qz + qw * qy);
            const float R10 = 2.f * (qx * qy + qw * qz);
            const float R11 = 1.f - 2.f * (qx * qx + qz * qz);
            const float R12 = 2.f * (qy * qz - qw * qx);
            const float R20 = 2.f * (qx * qz - qw * qy);
            const float R21 = 2.f * (qy * qz + qw * qx);
            const float R22 = 1.f - 2.f * (qx * qx + qy * qy);

            const float s0 = expf(svecb[3 * n + 0]);
            const float s1 = expf(svecb[3 * n + 1]);
            const float s2 = expf(svecb[3 * n + 2]);

            const float M00 = R00 * s0, M01 = R01 * s1, M02 = R02 * s2;
            const float M10 = R10 * s0, M11 = R11 * s1, M12 = R12 * s2;
            const float M20 = R20 * s0, M21 = R21 * s1, M22 = R22 * s2;
            const float V00 = M00 * M00 + M01 * M01 + M02 * M02;
            const float V01 = M00 * M10 + M01 * M11 + M02 * M12;
            const float V02 = M00 * M20 + M01 * M21 + M02 * M22;
            const float V11 = M10 * M10 + M11 * M11 + M12 * M12;
            const float V12 = M10 * M20 + M11 * M21 + M12 * M22;
            const float V22 = M20 * M20 + M21 * M21 + M22 * M22;

            const float A00 = Rw00 * V00 + Rw01 * V01 + Rw02 * V02;
            const float A01 = Rw00 * V01 + Rw01 * V11 + Rw02 * V12;
            const float A02 = Rw00 * V02 + Rw01 * V12 + Rw02 * V22;
            const float A10 = Rw10 * V00 + Rw11 * V01 + Rw12 * V02;
            const float A11 = Rw10 * V01 + Rw11 * V11 + Rw12 * V12;
            const float A12 = Rw10 * V02 + Rw11 * V12 + Rw12 * V22;
            const float A20 = Rw20 * V00 + Rw21 * V01 + Rw22 * V02;
            const float A21 = Rw20 * V01 + Rw21 * V11 + Rw22 * V12;
            const float A22 = Rw20 * V02 + Rw21 * V12 + Rw22 * V22;
            const float CC00 = A00 * Rw00 + A01 * Rw01 + A02 * Rw02;
            const float CC01 = A00 * Rw10 + A01 * Rw11 + A02 * Rw12;
            const float CC02 = A00 * Rw20 + A01 * Rw21 + A02 * Rw22;
            const float CC11 = A10 * Rw10 + A11 * Rw11 + A12 * Rw12;
            const float CC12 = A10 * Rw20 + A11 * Rw21 + A12 * Rw22;
            const float CC22 = A20 * Rw20 + A21 * Rw21 + A22 * Rw22;

            const float iz2 = iz * iz;
            const float j02 = -p0 * iz2, j12 = -p1 * iz2;
            const float T00 = iz * CC00 + j02 * CC02;
            const float T01 = iz * CC01 + j02 * CC12;
            const float T02 = iz * CC02 + j02 * CC22;
            const float T11 = iz * CC11 + j12 * CC12;
            const float T12 = iz * CC12 + j12 * CC22;
            const float c2d00 = T00 * iz + T02 * j02;
            const float c2d01 = T01 * iz + T02 * j12;
            const float c2d11 = T11 * iz + T12 * j12;

            const float a = c2d00 + 1e-8f;
            const float b = c2d01;
            const float c = c2d11 + 1e-8f;
            const float idet = 1.0f / (a * c - b * b);
            const float ia = c * idet, ib = -b * idet, ic = a * idet;

            qa = -0.5f * ia * L2E;
            const float qb = -ib * L2E;
            const float qc = -0.5f * ic * L2E;
            const float alpha = 1.0f / (1.0f + expf(-alphab[n]));
            const float la = log2f(alpha);
            cr = 1.0f / (1.0f + expf(-SH_BASE_F * shc[27 * n + 0]));
            cg = 1.0f / (1.0f + expf(-SH_BASE_F * shc[27 * n + 9]));
            cb = 1.0f / (1.0f + expf(-SH_BASE_F * shc[27 * n + 18]));

            // Row cull: max over dx of qa*dx^2 + B*dx + Cc (qa < 0).
            const float dy = py - my;
            B  = qb * dy;
            Cc = fmaf(qc * dy, dy, la);
            const float pmax = Cc - (B * B) / (4.0f * qa);
            keep = (pmax > LOG2EPS);
            // Composite stable key: primary z bits, secondary original index.
            zk = ((unsigned long long)__float_as_uint(z) << 32) | (unsigned)n;
        }

        const unsigned long long mask = __ballot(keep);
        if (wlane == 0) wcnt[wid] = __popcll(mask);
        __syncthreads();
        int base = cnt;
#pragma unroll
        for (int w = 0; w < 4; ++w) base += (w < wid) ? wcnt[w] : 0;
        if (keep) {
            const int slot = base + __popcll(mask & lanemask);
            comp[slot][0] = make_float4(mx, qa, B, Cc);
            comp[slot][1] = make_float4(cr, cg, cb, 0.f);
            skey[slot] = zk;
        }
        cnt += wcnt[0] + wcnt[1] + wcnt[2] + wcnt[3];
        __syncthreads();
    }

    // Pad to multiple of 32 with zero-contribution entries; pad keys are
    // distinct and sort to the end (zbits=0xFFFFFFFF impossible for real z).
    const int M = cnt;
    const int pad = (32 - (M & 31)) & 31;
    if (tid < pad) {
        comp[M + tid][0] = make_float4(0.f, 0.f, 0.f, -1000.f);
        comp[M + tid][1] = make_float4(0.f, 0.f, 0.f, 0.f);
        skey[M + tid] = 0xFFFFFFFF00000000ull | (unsigned)(M + tid);
    }
    __syncthreads();
    const int Mp = M + pad;   // multiple of 32, <= NG

    // ---------------- Phase B: stable rank sort of survivors ----------------
    // All keys distinct => rank is a permutation. Broadcast b128 key reads.
    // Static q-indexing keeps sr0/sr1/srk in registers (no scratch).
    float4 sr0[4], sr1[4];
    int srk[4];
#pragma unroll
    for (int q = 0; q < 4; ++q) {
        const int s = q * 256 + tid;
        if (s < Mp) {
            const unsigned long long k = skey[s];
            int rank = 0;
            for (int jb = 0; jb < (Mp >> 1); ++jb) {
                const ulonglong2 kk = skey2[jb];   // broadcast, conflict-free
                rank += (kk.x < k) ? 1 : 0;
                rank += (kk.y < k) ? 1 : 0;
            }
            sr0[q] = comp[s][0];
            sr1[q] = comp[s][1];
            srk[q] = rank;
        }
    }
    __syncthreads();
#pragma unroll
    for (int q = 0; q < 4; ++q) {
        const int s = q * 256 + tid;
        if (s < Mp) {
            comp[srk[q]][0] = sr0[q];
            comp[srk[q]][1] = sr1[q];
        }
    }
    __syncthreads();

    // ---------------- Phase C: front-to-back composite ----------------
    const float px = ((float)tid + 0.5f - (float)IMG_W * 0.5f) / (float)IMG_W;
    float T = 1.0f;
    float ar = 0.f, ag = 0.f, ab = 0.f;
    for (int mb = 0; mb < Mp; mb += 32) {
#pragma unroll 8
        for (int k = 0; k < 32; ++k) {
            const int m = mb + k;
            const float4 c0 = comp[m][0];          // mx,qa,B,Cc (broadcast)
            const float4 c1 = comp[m][1];          // r,g,b,-
            const float dx = px - c0.x;
            const float p  = fmaf(dx, fmaf(c0.y, dx, c0.z), c0.w);
            const float w  = __builtin_amdgcn_exp2f(p);
            const float wT = w * T;
            ar = fmaf(wT, c1.x, ar);
            ag = fmaf(wT, c1.y, ag);
            ab = fmaf(wT, c1.z, ab);
            T = fmaf(-fminf(w, 0.9999f), T, T);
        }
        if (__all(T <= 0.0001f)) break;            // wave-uniform exit
    }

    const int o = (row * IMG_W + tid) * 3;
    out[o + 0] = ar;
    out[o + 1] = ag;
    out[o + 2] = ab;
}

extern "C" void kernel_launch(void* const* d_in, const int* in_sizes, int n_in,
                              void* d_out, int out_size, void* d_ws, size_t ws_size,
                              hipStream_t stream)
{
    const float* mean   = (const float*)d_in[0];
    const float* qvec   = (const float*)d_in[1];
    const float* svecb  = (const float*)d_in[2];
    const float* shc    = (const float*)d_in[3];
    const float* alphab = (const float*)d_in[4];
    const float* c2w    = (const float*)d_in[5];

    const int N = in_sizes[0] / 3;   // 1024

    fused_render_kernel<<<IMG_H, 256, 0, stream>>>(
        mean, qvec, svecb, shc, alphab, c2w, (float*)d_out, N);
}

// Round 2
// 76.226 us; speedup vs baseline: 1.2228x; 1.0326x over previous
//
#include <hip/hip_runtime.h>

// Instance fixed by setup_inputs(): N=1024 gaussians, H=W=256.
// SINGLE fused kernel: one block per image row.
//   Phase A1: cheap CONSERVATIVE pre-cull (row-max upper bound via
//             c_yy <= iz^2(1+my^2)*s_max^2, la <= 0). Guaranteed superset
//             of the exact survivor set -> output bit-identical.
//             Unordered ballot+atomic index compaction (order irrelevant:
//             Phase B sorts by (z,idx) keys anyway).
//   Phase A2: full preprocess + EXACT cull test only on ~15% survivors.
//   Phase B : stable rank sort of survivors by (zbits, idx).
//   Phase C : front-to-back composite.
#define IMG_H 256
#define IMG_W 256
#define NG 1024
#define SH_BASE_F 0.28209479177387814f
#define L2E 1.4426950408889634f
#define LOG2EPS -26.575424759098898f   // log2(1e-8) cull threshold
#define PRECULL_K 37.5f                // 2*26.575/1.4427 = 36.84 + margin

__global__ __launch_bounds__(256) void fused_render_kernel(
    const float* __restrict__ mean,
    const float* __restrict__ qvec,
    const float* __restrict__ svecb,
    const float* __restrict__ shc,
    const float* __restrict__ alphab,
    const float* __restrict__ c2w,
    float* __restrict__ out,
    int N)
{
    __shared__ float4 comp[NG][2];        // 32 KB: [mx,qa,B,Cc][r,g,b,-]
    __shared__ ulonglong2 skey2[NG / 2];  // 8 KB, 16B-aligned for b128 reads
    __shared__ int idxbuf[NG];            // 4 KB: pre-cull survivor indices
    __shared__ int cntp, cnt;
    unsigned long long* skey = (unsigned long long*)skey2;

    const int tid = threadIdx.x;
    const int row = blockIdx.x;
    const float py = ((float)row + 0.5f - (float)IMG_H * 0.5f) / (float)IMG_W;
    const int wlane = tid & 63;
    const unsigned long long lanemask = (1ull << wlane) - 1ull;

    if (tid == 0) { cntp = 0; cnt = 0; }

    // Uniform camera matrix (scalar loads, L2-resident).
    float C[16];
#pragma unroll
    for (int k = 0; k < 16; ++k) C[k] = c2w[k];
    const float t0 = C[3], t1 = C[7], t2 = C[11];
    const float Rw00 = C[0], Rw01 = C[4], Rw02 = C[8];
    const float Rw10 = C[1], Rw11 = C[5], Rw12 = C[9];
    const float Rw20 = C[2], Rw21 = C[6], Rw22 = C[10];

    __syncthreads();   // cntp/cnt init visible

    // ------------- Phase A1: conservative pre-cull + index compact -------------
#pragma unroll
    for (int r = 0; r < 4; ++r) {
        const int n = r * 256 + tid;
        bool keepp = false;
        if (n < N) {
            const float d0 = mean[3 * n + 0] - t0;
            const float d1 = mean[3 * n + 1] - t1;
            const float d2 = mean[3 * n + 2] - t2;
            const float p1 = Rw10 * d0 + Rw11 * d1 + Rw12 * d2;
            const float p2 = Rw20 * d0 + Rw21 * d1 + Rw22 * d2;
            const float z  = fmaxf(p2, 0.001f);
            const float iz = 1.0f / z;
            const float my = p1 * iz;
            const float dy = py - my;
            const float sb0 = svecb[3 * n + 0];
            const float sb1 = svecb[3 * n + 1];
            const float sb2 = svecb[3 * n + 2];
            const float s2max = expf(2.0f * fmaxf(fmaxf(sb0, sb1), sb2));
            // c_yy upper bound: iz^2 (1+my^2) s_max^2  (+ regularizer)
            const float cub = iz * iz * fmaf(my, my, 1.0f) * s2max + 1e-8f;
            keepp = (dy * dy <= PRECULL_K * cub);
        }
        const unsigned long long m = __ballot(keepp);
        int base = 0;
        if (wlane == 0) base = atomicAdd(&cntp, __popcll(m));
        base = __shfl(base, 0);
        if (keepp) idxbuf[base + __popcll(m & lanemask)] = n;
    }
    __syncthreads();
    const int Mpre = cntp;

    // ------------- Phase A2: full preprocess + exact cull on survivors -------------
    const int rounds = (Mpre + 255) >> 8;
    for (int q = 0; q < rounds; ++q) {
        const int s = q * 256 + tid;
        bool keep = false;
        float mx = 0.f, qa = 0.f, B = 0.f, Cc = 0.f, cr = 0.f, cg = 0.f, cb = 0.f;
        unsigned long long zk = 0;
        if (s < Mpre) {
            const int n = idxbuf[s];
            const float d0 = mean[3 * n + 0] - t0;
            const float d1 = mean[3 * n + 1] - t1;
            const float d2 = mean[3 * n + 2] - t2;
            const float p0 = Rw00 * d0 + Rw01 * d1 + Rw02 * d2;
            const float p1 = Rw10 * d0 + Rw11 * d1 + Rw12 * d2;
            const float p2 = Rw20 * d0 + Rw21 * d1 + Rw22 * d2;

            const float z  = fmaxf(p2, 0.001f);
            const float iz = 1.0f / z;
            mx = p0 * iz;
            const float my = p1 * iz;

            const float4 q4 = ((const float4*)qvec)[n];
            float qw = q4.x, qx = q4.y, qy = q4.z, qz = q4.w;
            const float qinv = 1.0f / sqrtf(qw * qw + qx * qx + qy * qy + qz * qz);
            qw *= qinv; qx *= qinv; qy *= qinv; qz *= qinv;
            const float R00 = 1.f - 2.f * (qy * qy + qz * qz);
            const float R01 = 2.f * (qx * qy - qw * qz);
            const float R02 = 2.f * (qx * qz + qw * qy);
            const float R10 = 2.f * (qx * qy + qw * qz);
            const float R11 = 1.f - 2.f * (qx * qx + qz * qz);
            const float R12 = 2.f * (qy * qz - qw * qx);
            const float R20 = 2.f * (qx * qz - qw * qy);
            const float R21 = 2.f * (qy * qz + qw * qx);
            const float R22 = 1.f - 2.f * (qx * qx + qy * qy);

            const float s0 = expf(svecb[3 * n + 0]);
            const float s1 = expf(svecb[3 * n + 1]);
            const float s2 = expf(svecb[3 * n + 2]);

            const float M00 = R00 * s0, M01 = R01 * s1, M02 = R02 * s2;
            const float M10 = R10 * s0, M11 = R11 * s1, M12 = R12 * s2;
            const float M20 = R20 * s0, M21 = R21 * s1, M22 = R22 * s2;
            const float V00 = M00 * M00 + M01 * M01 + M02 * M02;
            const float V01 = M00 * M10 + M01 * M11 + M02 * M12;
            const float V02 = M00 * M20 + M01 * M21 + M02 * M22;
            const float V11 = M10 * M10 + M11 * M11 + M12 * M12;
            const float V12 = M10 * M20 + M11 * M21 + M12 * M22;
            const float V22 = M20 * M20 + M21 * M21 + M22 * M22;

            const float A00 = Rw00 * V00 + Rw01 * V01 + Rw02 * V02;
            const float A01 = Rw00 * V01 + Rw01 * V11 + Rw02 * V12;
            const float A02 = Rw00 * V02 + Rw01 * V12 + Rw02 * V22;
            const float A10 = Rw10 * V00 + Rw11 * V01 + Rw12 * V02;
            const float A11 = Rw10 * V01 + Rw11 * V11 + Rw12 * V12;
            const float A12 = Rw10 * V02 + Rw11 * V12 + Rw12 * V22;
            const float A20 = Rw20 * V00 + Rw21 * V01 + Rw22 * V02;
            const float A21 = Rw20 * V01 + Rw21 * V11 + Rw22 * V12;
            const float A22 = Rw20 * V02 + Rw21 * V12 + Rw22 * V22;
            const float CC00 = A00 * Rw00 + A01 * Rw01 + A02 * Rw02;
            const float CC01 = A00 * Rw10 + A01 * Rw11 + A02 * Rw12;
            const float CC02 = A00 * Rw20 + A01 * Rw21 + A02 * Rw22;
            const float CC11 = A10 * Rw10 + A11 * Rw11 + A12 * Rw12;
            const float CC12 = A10 * Rw20 + A11 * Rw21 + A12 * Rw22;
            const float CC22 = A20 * Rw20 + A21 * Rw21 + A22 * Rw22;

            const float iz2 = iz * iz;
            const float j02 = -p0 * iz2, j12 = -p1 * iz2;
            const float T00 = iz * CC00 + j02 * CC02;
            const float T01 = iz * CC01 + j02 * CC12;
            const float T02 = iz * CC02 + j02 * CC22;
            const float T11 = iz * CC11 + j12 * CC12;
            const float T12 = iz * CC12 + j12 * CC22;
            const float c2d00 = T00 * iz + T02 * j02;
            const float c2d01 = T01 * iz + T02 * j12;
            const float c2d11 = T11 * iz + T12 * j12;

            const float a = c2d00 + 1e-8f;
            const float b = c2d01;
            const float c = c2d11 + 1e-8f;
            const float idet = 1.0f / (a * c - b * b);
            const float ia = c * idet, ib = -b * idet, ic = a * idet;

            qa = -0.5f * ia * L2E;
            const float qb = -ib * L2E;
            const float qc = -0.5f * ic * L2E;
            const float alpha = 1.0f / (1.0f + expf(-alphab[n]));
            const float la = log2f(alpha);
            cr = 1.0f / (1.0f + expf(-SH_BASE_F * shc[27 * n + 0]));
            cg = 1.0f / (1.0f + expf(-SH_BASE_F * shc[27 * n + 9]));
            cb = 1.0f / (1.0f + expf(-SH_BASE_F * shc[27 * n + 18]));

            // Exact row cull: max over dx of qa*dx^2 + B*dx + Cc (qa < 0).
            const float dy = py - my;
            B  = qb * dy;
            Cc = fmaf(qc * dy, dy, la);
            const float pmax = Cc - (B * B) / (4.0f * qa);
            keep = (pmax > LOG2EPS);
            // Composite stable key: primary z bits, secondary original index.
            zk = ((unsigned long long)__float_as_uint(z) << 32) | (unsigned)n;
        }

        const unsigned long long m = __ballot(keep);
        int base = 0;
        if (wlane == 0) base = atomicAdd(&cnt, __popcll(m));
        base = __shfl(base, 0);
        if (keep) {
            const int slot = base + __popcll(m & lanemask);
            comp[slot][0] = make_float4(mx, qa, B, Cc);
            comp[slot][1] = make_float4(cr, cg, cb, 0.f);
            skey[slot] = zk;
        }
    }
    __syncthreads();

    // Pad to multiple of 32 with zero-contribution entries; pad keys are
    // distinct and sort to the end (zbits=0xFFFFFFFF impossible for real z).
    const int M = cnt;
    const int pad = (32 - (M & 31)) & 31;
    if (tid < pad) {
        comp[M + tid][0] = make_float4(0.f, 0.f, 0.f, -1000.f);
        comp[M + tid][1] = make_float4(0.f, 0.f, 0.f, 0.f);
        skey[M + tid] = 0xFFFFFFFF00000000ull | (unsigned)(M + tid);
    }
    __syncthreads();
    const int Mp = M + pad;   // multiple of 32, <= NG

    // ---------------- Phase B: stable rank sort of survivors ----------------
    // All keys distinct => rank is a permutation; initial placement order is
    // irrelevant. Broadcast b128 key reads, conflict-free.
    float4 sr0[4], sr1[4];
    int srk[4];
#pragma unroll
    for (int q = 0; q < 4; ++q) {
        const int s = q * 256 + tid;
        if (s < Mp) {
            const unsigned long long k = skey[s];
            int rank = 0;
            for (int jb = 0; jb < (Mp >> 1); ++jb) {
                const ulonglong2 kk = skey2[jb];   // broadcast, conflict-free
                rank += (kk.x < k) ? 1 : 0;
                rank += (kk.y < k) ? 1 : 0;
            }
            sr0[q] = comp[s][0];
            sr1[q] = comp[s][1];
            srk[q] = rank;
        }
    }
    __syncthreads();
#pragma unroll
    for (int q = 0; q < 4; ++q) {
        const int s = q * 256 + tid;
        if (s < Mp) {
            comp[srk[q]][0] = sr0[q];
            comp[srk[q]][1] = sr1[q];
        }
    }
    __syncthreads();

    // ---------------- Phase C: front-to-back composite ----------------
    const float px = ((float)tid + 0.5f - (float)IMG_W * 0.5f) / (float)IMG_W;
    float T = 1.0f;
    float ar = 0.f, ag = 0.f, ab = 0.f;
    for (int mb = 0; mb < Mp; mb += 32) {
#pragma unroll 8
        for (int k = 0; k < 32; ++k) {
            const int m = mb + k;
            const float4 c0 = comp[m][0];          // mx,qa,B,Cc (broadcast)
            const float4 c1 = comp[m][1];          // r,g,b,-
            const float dx = px - c0.x;
            const float p  = fmaf(dx, fmaf(c0.y, dx, c0.z), c0.w);
            const float w  = __builtin_amdgcn_exp2f(p);
            const float wT = w * T;
            ar = fmaf(wT, c1.x, ar);
            ag = fmaf(wT, c1.y, ag);
            ab = fmaf(wT, c1.z, ab);
            T = fmaf(-fminf(w, 0.9999f), T, T);
        }
        if (__all(T <= 0.0001f)) break;            // wave-uniform exit
    }

    const int o = (row * IMG_W + tid) * 3;
    out[o + 0] = ar;
    out[o + 1] = ag;
    out[o + 2] = ab;
}

extern "C" void kernel_launch(void* const* d_in, const int* in_sizes, int n_in,
                              void* d_out, int out_size, void* d_ws, size_t ws_size,
                              hipStream_t stream)
{
    const float* mean   = (const float*)d_in[0];
    const float* qvec   = (const float*)d_in[1];
    const float* svecb  = (const float*)d_in[2];
    const float* shc    = (const float*)d_in[3];
    const float* alphab = (const float*)d_in[4];
    const float* c2w    = (const float*)d_in[5];

    const int N = in_sizes[0] / 3;   // 1024

    fused_render_kernel<<<IMG_H, 256, 0, stream>>>(
        mean, qvec, svecb, shc, alphab, c2w, (float*)d_out, N);
}